// Round 1
// baseline (1548.212 us; speedup 1.0000x reference)
//
#include <hip/hip_runtime.h>
#include <math.h>

#define EPS 1e-6f
constexpr int D = 128;

// ---------------- row norms: one wave per row, lane holds 2 of 128 dims ----
__global__ __launch_bounds__(256)
void norms_kernel(const float* __restrict__ pts, int rows, float eps,
                  float* __restrict__ out) {
    int wave = (blockIdx.x * blockDim.x + threadIdx.x) >> 6;
    int lane = threadIdx.x & 63;
    if (wave >= rows) return;
    const float2* p = (const float2*)(pts + (size_t)wave * D);
    float2 v = p[lane];
    float a = v.x + eps, b = v.y + eps;
    float s = a * a + b * b;
    #pragma unroll
    for (int off = 32; off > 0; off >>= 1) s += __shfl_down(s, off);
    if (lane == 0) out[wave] = s;
}

// ---------------- fused dist-GEMM + exp + column reduction ------------------
// colOut[i] += sum_j exp(bias[j] - (||a_j - b_i|| + EPS)),  a = A + epsA
// d2 = normA[j] + normB[i] - 2 * dot(a_j, b_i)
#define TJ 64
#define TI 64
#define KT 16
#define PAD 4

__global__ __launch_bounds__(256)
void dist_col_kernel(const float* __restrict__ A, float epsA,
                     const float* __restrict__ B,
                     const float* __restrict__ normA,
                     const float* __restrict__ normB,
                     const float* __restrict__ bias,
                     float* __restrict__ colOut) {
    __shared__ float As[KT][TJ + PAD];
    __shared__ float Bs[KT][TI + PAD];
    __shared__ float red[16][64];

    const int tid = threadIdx.x;
    const int tx = tid & 15;        // i micro-tile selector
    const int ty = tid >> 4;        // j micro-tile selector
    const int i0 = blockIdx.x * TI;
    const int j0 = blockIdx.y * TJ;

    const int lrow  = tid >> 2;       // 0..63: tile row to load
    const int lcol4 = (tid & 3) * 4;  // 0,4,8,12: k sub-chunk

    float acc[4][4] = {};

    for (int k0 = 0; k0 < D; k0 += KT) {
        const float4 av = *(const float4*)(A + (size_t)(j0 + lrow) * D + k0 + lcol4);
        const float4 bv = *(const float4*)(B + (size_t)(i0 + lrow) * D + k0 + lcol4);
        As[lcol4 + 0][lrow] = av.x + epsA;
        As[lcol4 + 1][lrow] = av.y + epsA;
        As[lcol4 + 2][lrow] = av.z + epsA;
        As[lcol4 + 3][lrow] = av.w + epsA;
        Bs[lcol4 + 0][lrow] = bv.x;
        Bs[lcol4 + 1][lrow] = bv.y;
        Bs[lcol4 + 2][lrow] = bv.z;
        Bs[lcol4 + 3][lrow] = bv.w;
        __syncthreads();
        #pragma unroll
        for (int k = 0; k < KT; ++k) {
            const float4 aF = *(const float4*)&As[k][ty * 4];
            const float4 bF = *(const float4*)&Bs[k][tx * 4];
            const float am[4] = {aF.x, aF.y, aF.z, aF.w};
            const float bn[4] = {bF.x, bF.y, bF.z, bF.w};
            #pragma unroll
            for (int m = 0; m < 4; ++m)
                #pragma unroll
                for (int n = 0; n < 4; ++n)
                    acc[m][n] = fmaf(am[m], bn[n], acc[m][n]);
        }
        __syncthreads();
    }

    // epilogue: d = sqrt(max(d2,0)); val = exp(bias_j - d - EPS); reduce over j
    float colv[4] = {0.f, 0.f, 0.f, 0.f};
    #pragma unroll
    for (int m = 0; m < 4; ++m) {
        const int j = j0 + ty * 4 + m;
        const float na = normA[j];
        const float bj = bias[j];
        #pragma unroll
        for (int n = 0; n < 4; ++n) {
            const int i = i0 + tx * 4 + n;
            const float d2 = na + normB[i] - 2.0f * acc[m][n];
            const float d = sqrtf(fmaxf(d2, 0.0f));
            colv[n] += __expf(bj - d - EPS);
        }
    }
    *(float4*)&red[ty][tx * 4] = *(const float4*)colv;
    __syncthreads();
    if (tid < 64) {
        float s = 0.0f;
        #pragma unroll
        for (int r = 0; r < 16; ++r) s += red[r][tid];
        atomicAdd(&colOut[i0 + tid], s);
    }
}

// ---------------- link (edge) term: one wave per edge -----------------------
__global__ __launch_bounds__(256)
void edge_kernel(const float* __restrict__ L, const float* __restrict__ R,
                 const float* __restrict__ U,
                 const float* __restrict__ rho, const float* __restrict__ nu,
                 const float* __restrict__ tau, const float* __restrict__ w,
                 const int* __restrict__ si, const int* __restrict__ sj,
                 const int* __restrict__ sk, int E,
                 float* __restrict__ out) {
    const int lane = threadIdx.x & 63;
    const int wv = threadIdx.x >> 6;
    const int wavesPerBlock = blockDim.x >> 6;
    const int gwave = blockIdx.x * wavesPerBlock + wv;
    const int nwaves = gridDim.x * wavesPerBlock;

    float partial = 0.0f;
    for (int e = gwave; e < E; e += nwaves) {
        const int i = si[e], j = sj[e], k = sk[e];
        const float2 lv = *(const float2*)(L + (size_t)i * D + lane * 2);
        const float2 rv = *(const float2*)(R + (size_t)j * D + lane * 2);
        const float2 uv = *(const float2*)(U + (size_t)k * D + lane * 2);
        const float a0 = lv.x - rv.x + EPS, a1 = lv.y - rv.y + EPS;
        const float b0 = lv.x - uv.x + EPS, b1 = lv.y - uv.y + EPS;
        float slr = a0 * a0 + a1 * a1;
        float slu = b0 * b0 + b1 * b1;
        #pragma unroll
        for (int off = 32; off > 0; off >>= 1) {
            slr += __shfl_down(slr, off);
            slu += __shfl_down(slu, off);
        }
        if (lane == 0) {
            const float term = rho[i] + nu[j] + tau[k] - sqrtf(slr) - sqrtf(slu);
            partial += w[e] * term;
        }
    }
    __shared__ float ps[8];
    if (lane == 0) ps[wv] = partial;
    __syncthreads();
    if (threadIdx.x == 0) {
        float s = 0.0f;
        for (int q = 0; q < wavesPerBlock; ++q) s += ps[q];
        atomicAdd(out, s);
    }
}

// ---------------- z_pdist1 = sum_i colRL[i] * exp(rho_i) * colUL[i] ---------
__global__ __launch_bounds__(256)
void combine_kernel(const float* __restrict__ colRL,
                    const float* __restrict__ colUL,
                    const float* __restrict__ rho, int nI,
                    float* __restrict__ out) {
    const int t = blockIdx.x * blockDim.x + threadIdx.x;
    float v = 0.0f;
    if (t < nI) v = colRL[t] * __expf(rho[t]) * colUL[t];
    #pragma unroll
    for (int off = 32; off > 0; off >>= 1) v += __shfl_down(v, off);
    __shared__ float ps[4];
    const int lane = threadIdx.x & 63, wv = threadIdx.x >> 6;
    if (lane == 0) ps[wv] = v;
    __syncthreads();
    if (threadIdx.x == 0) {
        atomicAdd(out, -(ps[0] + ps[1] + ps[2] + ps[3]));
    }
}

extern "C" void kernel_launch(void* const* d_in, const int* in_sizes, int n_in,
                              void* d_out, int out_size, void* d_ws, size_t ws_size,
                              hipStream_t stream) {
    (void)n_in; (void)out_size; (void)ws_size;
    const float* L   = (const float*)d_in[0];   // latent_l [I,128]
    const float* R   = (const float*)d_in[1];   // latent_r [J,128]
    const float* U   = (const float*)d_in[2];   // latent_u [K,128]
    const float* rho = (const float*)d_in[3];   // [I]
    const float* nu  = (const float*)d_in[4];   // [J]
    const float* tau = (const float*)d_in[5];   // [K]
    const float* w   = (const float*)d_in[6];   // [E]
    const int* si = (const int*)d_in[7];
    const int* sj = (const int*)d_in[8];
    const int* sk = (const int*)d_in[9];
    const int I = in_sizes[3];
    const int J = in_sizes[4];
    const int K = in_sizes[5];
    const int E = in_sizes[6];

    float* ws    = (float*)d_ws;
    float* colRL = ws;               // I
    float* colUL = ws + I;           // I
    float* normL = ws + 2 * I;       // I
    float* normR = ws + 3 * I;       // J
    float* normU = ws + 3 * I + J;   // K

    hipMemsetAsync(d_out, 0, sizeof(float), stream);
    hipMemsetAsync(colRL, 0, (size_t)2 * I * sizeof(float), stream);

    // row norms (eps folded for R and U, per reference: cdist(r+EPS, l))
    norms_kernel<<<dim3((I * 64) / 256), 256, 0, stream>>>(L, I, 0.0f, normL);
    norms_kernel<<<dim3((J * 64) / 256), 256, 0, stream>>>(R, J, EPS, normR);
    norms_kernel<<<dim3((K * 64) / 256), 256, 0, stream>>>(U, K, EPS, normU);

    // col_rl[i] = sum_j exp(nu_j - d_rl[j,i]),  col_ul_raw[i] = sum_k exp(tau_k - d_ul[k,i])
    dist_col_kernel<<<dim3(I / TI, J / TJ), 256, 0, stream>>>(
        R, EPS, L, normR, normL, nu, colRL);
    dist_col_kernel<<<dim3(I / TI, K / TJ), 256, 0, stream>>>(
        U, EPS, L, normU, normL, tau, colUL);

    // link term accumulates +z_pdist2 into out
    edge_kernel<<<dim3(4096), 256, 0, stream>>>(L, R, U, rho, nu, tau, w,
                                                si, sj, sk, E, (float*)d_out);

    // subtract z_pdist1
    combine_kernel<<<dim3((I + 255) / 256), 256, 0, stream>>>(
        colRL, colUL, rho, I, (float*)d_out);
}

// Round 2
// 688.777 us; speedup vs baseline: 2.2478x; 2.2478x over previous
//
#include <hip/hip_runtime.h>
#include <math.h>

#define EPS 1e-6f
#define LOG2E 1.44269504f
constexpr int D = 128;

typedef short bf16x8 __attribute__((ext_vector_type(8)));
typedef float f32x4  __attribute__((ext_vector_type(4)));

__device__ inline unsigned short f2bf(float x) {
    unsigned u = __float_as_uint(x);
    return (unsigned short)((u + 0x7fffu + ((u >> 16) & 1u)) >> 16);
}

// ---- prep: fp32 row -> bf16 row (RNE), plus fused row norm of (x+eps) ------
__global__ __launch_bounds__(256)
void prep_kernel(const float* __restrict__ in, int rows, float eps,
                 unsigned* __restrict__ outb, float* __restrict__ norms) {
    int gw = (blockIdx.x * blockDim.x + threadIdx.x) >> 6;
    int lane = threadIdx.x & 63;
    if (gw >= rows) return;
    float2 v = ((const float2*)(in + (size_t)gw * D))[lane];
    outb[(size_t)gw * 64 + lane] = (unsigned)f2bf(v.x) | ((unsigned)f2bf(v.y) << 16);
    float a = v.x + eps, b = v.y + eps;
    float s = a * a + b * b;
    #pragma unroll
    for (int off = 32; off > 0; off >>= 1) s += __shfl_down(s, off);
    if (lane == 0) norms[gw] = s;
}

// ---- fused dist-GEMM (MFMA bf16) + exp + column reduction ------------------
// colOut[i] += sum_j exp(bias[j] - (sqrt(normA[j]+normB[i]-2*dot(a_j,b_i)) + EPS))
// Block: 128 j x 128 i, K = 128 (full). 4 waves, each 64x64 via 4x4 tiles of
// 16x16x32 MFMA. LDS: two 32 KB tiles, 256 B rows, 16 B chunks XOR-swizzled
// by (row&15) -> conflict-minimal ds_read_b128 and ds_write_b128.
__global__ __launch_bounds__(256, 2)
void dist_mfma_kernel(const unsigned short* __restrict__ Ab,  // [J,128] bf16 (j rows)
                      const unsigned short* __restrict__ Bb,  // [I,128] bf16 (i rows)
                      const float* __restrict__ normA,
                      const float* __restrict__ normB,
                      const float* __restrict__ bias,
                      float* __restrict__ colOut) {
    __shared__ __align__(16) unsigned char smem[65536];
    const int tid = threadIdx.x;
    const int i0 = blockIdx.x * 128;
    const int j0 = blockIdx.y * 128;

    // stage A tile -> smem[0,32K), B tile -> smem[32K,64K)
    {
        const uint4* gA = (const uint4*)(Ab + (size_t)j0 * D);  // 2048 uint4, contiguous
        const uint4* gB = (const uint4*)(Bb + (size_t)i0 * D);
        #pragma unroll
        for (int it = 0; it < 8; ++it) {
            const int idx = it * 256 + tid;
            const int p = idx << 4;            // byte pos within 32 KB tile
            const int row = p >> 8;            // 0..127
            const int c16 = (p >> 4) & 15;     // 16B chunk within row
            const int dst = (row << 8) + (((c16) ^ (row & 15)) << 4);
            *(uint4*)(smem + dst)         = gA[idx];
            *(uint4*)(smem + 32768 + dst) = gB[idx];
        }
    }
    __syncthreads();

    const int lane = tid & 63;
    const int wave = tid >> 6;
    const int m = lane & 15;       // MFMA row/col selector within 16
    const int q = lane >> 4;       // quad 0..3
    const int wj0 = (wave & 1) * 64;
    const int wi0 = (wave >> 1) * 64;

    const f32x4 zero = {0.f, 0.f, 0.f, 0.f};
    f32x4 acc[4][4];
    #pragma unroll
    for (int jt = 0; jt < 4; ++jt)
        #pragma unroll
        for (int it = 0; it < 4; ++it) acc[jt][it] = zero;

    #pragma unroll
    for (int c = 0; c < 4; ++c) {              // k-chunks of 32
        const int swz = ((c * 4 + q) ^ m) << 4;
        bf16x8 af[4], bfr[4];
        #pragma unroll
        for (int jt = 0; jt < 4; ++jt) {
            const int row = wj0 + jt * 16 + m;
            af[jt] = *(const bf16x8*)(smem + (row << 8) + swz);
        }
        #pragma unroll
        for (int it = 0; it < 4; ++it) {
            const int row = wi0 + it * 16 + m;
            bfr[it] = *(const bf16x8*)(smem + 32768 + (row << 8) + swz);
        }
        #pragma unroll
        for (int jt = 0; jt < 4; ++jt)
            #pragma unroll
            for (int it = 0; it < 4; ++it)
                acc[jt][it] = __builtin_amdgcn_mfma_f32_16x16x32_bf16(
                    af[jt], bfr[it], acc[jt][it], 0, 0, 0);
    }

    // epilogue: d2 -> sqrt -> exp -> column (i) sums
    float nb[4];
    #pragma unroll
    for (int it = 0; it < 4; ++it) nb[it] = normB[i0 + wi0 + it * 16 + m];

    float colsum[4] = {0.f, 0.f, 0.f, 0.f};
    #pragma unroll
    for (int jt = 0; jt < 4; ++jt) {
        const int jb = j0 + wj0 + jt * 16 + q * 4;
        #pragma unroll
        for (int r = 0; r < 4; ++r) {
            const float na = normA[jb + r];
            const float eb = bias[jb + r] - EPS;
            #pragma unroll
            for (int it = 0; it < 4; ++it) {
                const float d2 = na + nb[it] - 2.0f * acc[jt][it][r];
                const float dd = sqrtf(fmaxf(d2, 0.0f));
                colsum[it] += exp2f((eb - dd) * LOG2E);
            }
        }
    }
    // reduce across quads (lanes m, m+16, m+32, m+48 hold same i-column)
    #pragma unroll
    for (int it = 0; it < 4; ++it) {
        float s = colsum[it];
        s += __shfl_xor(s, 16);
        s += __shfl_xor(s, 32);
        colsum[it] = s;
    }

    __syncthreads();                       // tile reads done; alias smem as red
    float* red = (float*)smem;             // red[jhalf][ihalf][64]
    if (q == 0) {
        #pragma unroll
        for (int it = 0; it < 4; ++it)
            red[((wave & 1) * 2 + (wave >> 1)) * 64 + it * 16 + m] = colsum[it];
    }
    __syncthreads();
    if (tid < 128) {
        const int ih = tid >> 6, idx = tid & 63;
        const float s = red[(0 * 2 + ih) * 64 + idx] + red[(1 * 2 + ih) * 64 + idx];
        atomicAdd(&colOut[i0 + tid], s);
    }
}

// ---- link (edge) term: one wave per edge, bf16 gathers ---------------------
__global__ __launch_bounds__(256)
void edge_kernel(const unsigned* __restrict__ Lb, const unsigned* __restrict__ Rb,
                 const unsigned* __restrict__ Ub,
                 const float* __restrict__ rho, const float* __restrict__ nu,
                 const float* __restrict__ tau, const float* __restrict__ w,
                 const int* __restrict__ si, const int* __restrict__ sj,
                 const int* __restrict__ sk, int E,
                 float* __restrict__ out) {
    const int lane = threadIdx.x & 63;
    const int wv = threadIdx.x >> 6;
    const int wavesPerBlock = blockDim.x >> 6;
    const int gwave = blockIdx.x * wavesPerBlock + wv;
    const int nwaves = gridDim.x * wavesPerBlock;

    float partial = 0.0f;
    for (int e = gwave; e < E; e += nwaves) {
        const int i = si[e], j = sj[e], k = sk[e];
        const unsigned lv = Lb[(size_t)i * 64 + lane];
        const unsigned rv = Rb[(size_t)j * 64 + lane];
        const unsigned uv = Ub[(size_t)k * 64 + lane];
        const float l0 = __uint_as_float(lv << 16);
        const float l1 = __uint_as_float(lv & 0xffff0000u);
        const float r0 = __uint_as_float(rv << 16);
        const float r1 = __uint_as_float(rv & 0xffff0000u);
        const float u0 = __uint_as_float(uv << 16);
        const float u1 = __uint_as_float(uv & 0xffff0000u);
        const float a0 = l0 - r0 + EPS, a1 = l1 - r1 + EPS;
        const float b0 = l0 - u0 + EPS, b1 = l1 - u1 + EPS;
        float slr = a0 * a0 + a1 * a1;
        float slu = b0 * b0 + b1 * b1;
        #pragma unroll
        for (int off = 32; off > 0; off >>= 1) {
            slr += __shfl_down(slr, off);
            slu += __shfl_down(slu, off);
        }
        if (lane == 0) {
            const float term = rho[i] + nu[j] + tau[k] - sqrtf(slr) - sqrtf(slu);
            partial += w[e] * term;
        }
    }
    __shared__ float ps[8];
    if (lane == 0) ps[wv] = partial;
    __syncthreads();
    if (threadIdx.x == 0) {
        float s = 0.0f;
        for (int qq = 0; qq < wavesPerBlock; ++qq) s += ps[qq];
        atomicAdd(out, s);
    }
}

// ---- z_pdist1 = sum_i colRL[i] * exp(rho_i) * colUL[i] ---------------------
__global__ __launch_bounds__(256)
void combine_kernel(const float* __restrict__ colRL,
                    const float* __restrict__ colUL,
                    const float* __restrict__ rho, int nI,
                    float* __restrict__ out) {
    const int t = blockIdx.x * blockDim.x + threadIdx.x;
    float v = 0.0f;
    if (t < nI) v = colRL[t] * __expf(rho[t]) * colUL[t];
    #pragma unroll
    for (int off = 32; off > 0; off >>= 1) v += __shfl_down(v, off);
    __shared__ float ps[4];
    const int lane = threadIdx.x & 63, wv = threadIdx.x >> 6;
    if (lane == 0) ps[wv] = v;
    __syncthreads();
    if (threadIdx.x == 0) {
        atomicAdd(out, -(ps[0] + ps[1] + ps[2] + ps[3]));
    }
}

extern "C" void kernel_launch(void* const* d_in, const int* in_sizes, int n_in,
                              void* d_out, int out_size, void* d_ws, size_t ws_size,
                              hipStream_t stream) {
    (void)n_in; (void)out_size; (void)ws_size;
    const float* L   = (const float*)d_in[0];   // latent_l [I,128]
    const float* R   = (const float*)d_in[1];   // latent_r [J,128]
    const float* U   = (const float*)d_in[2];   // latent_u [K,128]
    const float* rho = (const float*)d_in[3];   // [I]
    const float* nu  = (const float*)d_in[4];   // [J]
    const float* tau = (const float*)d_in[5];   // [K]
    const float* w   = (const float*)d_in[6];   // [E]
    const int* si = (const int*)d_in[7];
    const int* sj = (const int*)d_in[8];
    const int* sk = (const int*)d_in[9];
    const int I = in_sizes[3];
    const int J = in_sizes[4];
    const int K = in_sizes[5];
    const int E = in_sizes[6];

    float* ws    = (float*)d_ws;
    float* colRL = ws;               // I
    float* colUL = ws + I;           // I
    float* normL = ws + 2 * I;       // I
    float* normR = ws + 3 * I;       // J
    float* normU = ws + 3 * I + J;   // K
    unsigned short* Lb = (unsigned short*)(ws + 3 * (size_t)I + J + K);  // 16B-aligned
    unsigned short* Rb = Lb + (size_t)I * D;
    unsigned short* Ub = Rb + (size_t)J * D;

    hipMemsetAsync(d_out, 0, sizeof(float), stream);
    hipMemsetAsync(colRL, 0, (size_t)2 * I * sizeof(float), stream);

    // bf16 copies + fused norms (eps folded into norms for R and U)
    prep_kernel<<<dim3(I / 4), 256, 0, stream>>>(L, I, 0.0f, (unsigned*)Lb, normL);
    prep_kernel<<<dim3(J / 4), 256, 0, stream>>>(R, J, EPS,  (unsigned*)Rb, normR);
    prep_kernel<<<dim3(K / 4), 256, 0, stream>>>(U, K, EPS,  (unsigned*)Ub, normU);

    // col_rl[i] = sum_j exp(nu_j - d_rl[j,i]); col_ul_raw[i] = sum_k exp(tau_k - d_ul[k,i])
    dist_mfma_kernel<<<dim3(I / 128, J / 128), 256, 0, stream>>>(
        Rb, Lb, normR, normL, nu, colRL);
    dist_mfma_kernel<<<dim3(I / 128, K / 128), 256, 0, stream>>>(
        Ub, Lb, normU, normL, tau, colUL);

    // link term accumulates +z_pdist2 into out
    edge_kernel<<<dim3(4096), 256, 0, stream>>>(Lb ? (const unsigned*)Lb : 0,
                                                (const unsigned*)Rb,
                                                (const unsigned*)Ub,
                                                rho, nu, tau, w,
                                                si, sj, sk, E, (float*)d_out);

    // subtract z_pdist1
    combine_kernel<<<dim3((I + 255) / 256), 256, 0, stream>>>(
        colRL, colUL, rho, I, (float*)d_out);
}

// Round 3
// 411.846 us; speedup vs baseline: 3.7592x; 1.6724x over previous
//
#include <hip/hip_runtime.h>
#include <math.h>

#define EPS 1e-6f
#define LOG2E 1.44269504f
constexpr int D = 128;

typedef short bf16x8 __attribute__((ext_vector_type(8)));
typedef float f32x4  __attribute__((ext_vector_type(4)));
typedef float f32x2  __attribute__((ext_vector_type(2)));

__device__ inline unsigned short f2bf(float x) {
    unsigned u = __float_as_uint(x);
    return (unsigned short)((u + 0x7fffu + ((u >> 16) & 1u)) >> 16);
}

// ---- prep: fp32 row -> bf16 row + fp8 row + fused row norm of (x+eps) ------
__global__ __launch_bounds__(256)
void prep_kernel(const float* __restrict__ in, int rows, float eps,
                 unsigned* __restrict__ outb, unsigned short* __restrict__ outf8,
                 float* __restrict__ norms) {
    int gw = (blockIdx.x * blockDim.x + threadIdx.x) >> 6;
    int lane = threadIdx.x & 63;
    if (gw >= rows) return;
    float2 v = ((const float2*)(in + (size_t)gw * D))[lane];
    outb[(size_t)gw * 64 + lane] = (unsigned)f2bf(v.x) | ((unsigned)f2bf(v.y) << 16);
    if (outf8) {
        int p = __builtin_amdgcn_cvt_pk_fp8_f32(v.x, v.y, 0, false);
        outf8[(size_t)gw * 64 + lane] = (unsigned short)(p & 0xffff);
    }
    float a = v.x + eps, b = v.y + eps;
    float s = a * a + b * b;
    #pragma unroll
    for (int off = 32; off > 0; off >>= 1) s += __shfl_down(s, off);
    if (lane == 0) norms[gw] = s;
}

// ---- fused dist-GEMM (MFMA bf16) + exp + column reduction ------------------
// colOut[i] += sum_j exp(bias[j] - (sqrt(normA[j]+normB[i]-2*dot(a_j,b_i)) + EPS))
// Block: 128 j x 128 i. BK=64 slabs (2 per row), 32 KB LDS -> 3 blocks/CU.
// LDS rows 128 B, 16 B chunks XOR-swizzled by (row&7).
__global__ __launch_bounds__(256, 3)
void dist_mfma_kernel(const unsigned short* __restrict__ Ab,  // [J,128] bf16
                      const unsigned short* __restrict__ Bb,  // [I,128] bf16
                      const float* __restrict__ normA,
                      const float* __restrict__ normB,
                      const float* __restrict__ bias,
                      float* __restrict__ colOut) {
    __shared__ __align__(16) unsigned char smem[32768];
    const int tid = threadIdx.x;
    const int i0 = blockIdx.x * 128;
    const int j0 = blockIdx.y * 128;

    const int lane = tid & 63;
    const int wave = tid >> 6;
    const int m = lane & 15;
    const int q = lane >> 4;
    const int wj0 = (wave & 1) * 64;
    const int wi0 = (wave >> 1) * 64;

    const f32x4 zero = {0.f, 0.f, 0.f, 0.f};
    f32x4 acc[4][4];
    #pragma unroll
    for (int jt = 0; jt < 4; ++jt)
        #pragma unroll
        for (int it = 0; it < 4; ++it) acc[jt][it] = zero;

    #pragma unroll
    for (int k0 = 0; k0 < D; k0 += 64) {
        // stage A slab -> smem[0,16K), B slab -> smem[16K,32K)
        const uint4* gA = (const uint4*)(Ab + (size_t)j0 * D + k0);
        const uint4* gB = (const uint4*)(Bb + (size_t)i0 * D + k0);
        if (k0) __syncthreads();
        #pragma unroll
        for (int it = 0; it < 4; ++it) {
            const int idx = it * 256 + tid;      // 0..1023
            const int row = idx >> 3;            // 0..127
            const int c8 = idx & 7;
            const int dst = (row << 7) + ((c8 ^ (row & 7)) << 4);
            *(uint4*)(smem + dst)         = gA[row * 16 + c8];
            *(uint4*)(smem + 16384 + dst) = gB[row * 16 + c8];
        }
        __syncthreads();

        #pragma unroll
        for (int c = 0; c < 2; ++c) {
            const int swz = ((c * 4 + q) ^ (m & 7)) << 4;
            bf16x8 af[4], bfr[4];
            #pragma unroll
            for (int jt = 0; jt < 4; ++jt)
                af[jt] = *(const bf16x8*)(smem + ((wj0 + jt * 16 + m) << 7) + swz);
            #pragma unroll
            for (int it = 0; it < 4; ++it)
                bfr[it] = *(const bf16x8*)(smem + 16384 + ((wi0 + it * 16 + m) << 7) + swz);
            #pragma unroll
            for (int jt = 0; jt < 4; ++jt)
                #pragma unroll
                for (int it = 0; it < 4; ++it)
                    acc[jt][it] = __builtin_amdgcn_mfma_f32_16x16x32_bf16(
                        af[jt], bfr[it], acc[jt][it], 0, 0, 0);
        }
    }

    // epilogue: d2 -> sqrt -> exp -> column (i) sums
    float nb[4];
    #pragma unroll
    for (int it = 0; it < 4; ++it) nb[it] = normB[i0 + wi0 + it * 16 + m];

    float colsum[4] = {0.f, 0.f, 0.f, 0.f};
    #pragma unroll
    for (int jt = 0; jt < 4; ++jt) {
        const int jb = j0 + wj0 + jt * 16 + q * 4;
        #pragma unroll
        for (int r = 0; r < 4; ++r) {
            const float na = normA[jb + r];
            const float eb = bias[jb + r] - EPS;
            #pragma unroll
            for (int it = 0; it < 4; ++it) {
                const float d2 = na + nb[it] - 2.0f * acc[jt][it][r];
                const float dd = sqrtf(fmaxf(d2, 0.0f));
                colsum[it] += exp2f((eb - dd) * LOG2E);
            }
        }
    }
    #pragma unroll
    for (int it = 0; it < 4; ++it) {
        float s = colsum[it];
        s += __shfl_xor(s, 16);
        s += __shfl_xor(s, 32);
        colsum[it] = s;
    }

    __syncthreads();
    float* red = (float*)smem;             // red[4][64]
    if (q == 0) {
        #pragma unroll
        for (int it = 0; it < 4; ++it)
            red[((wave & 1) * 2 + (wave >> 1)) * 64 + it * 16 + m] = colsum[it];
    }
    __syncthreads();
    if (tid < 128) {
        const int ih = tid >> 6, idx = tid & 63;
        const float s = red[(0 * 2 + ih) * 64 + idx] + red[(1 * 2 + ih) * 64 + idx];
        atomicAdd(&colOut[i0 + tid], s);
    }
}

// ---- link (edge) term: fp8 tables, 16 lanes per edge, 4 edges/wave ---------
__global__ __launch_bounds__(256)
void edge_fp8_kernel(const uint2* __restrict__ Lf8, const uint2* __restrict__ Rf8,
                     const uint2* __restrict__ Uf8,
                     const float* __restrict__ rho, const float* __restrict__ nu,
                     const float* __restrict__ tau, const float* __restrict__ w,
                     const int* __restrict__ si, const int* __restrict__ sj,
                     const int* __restrict__ sk, int E,
                     float* __restrict__ out) {
    const int lane = threadIdx.x & 63;
    const int wv = threadIdx.x >> 6;
    const int sub = lane & 15;       // dim chunk: dims [sub*8, sub*8+8)
    const int eg  = lane >> 4;       // edge within wave (0..3)
    const int gwave = blockIdx.x * 4 + wv;
    const int nw = gridDim.x * 4;

    float partial = 0.0f;
    #pragma unroll 2
    for (int base = gwave * 4; base < E; base += nw * 4) {
        const int e = base + eg;
        const bool valid = (e < E);
        float slr = 0.0f, slu = 0.0f;
        int i = 0, j = 0, k = 0;
        if (valid) {
            i = si[e]; j = sj[e]; k = sk[e];
            const uint2 lq = Lf8[(size_t)i * 16 + sub];
            const uint2 rq = Rf8[(size_t)j * 16 + sub];
            const uint2 uq = Uf8[(size_t)k * 16 + sub];
            const f32x2 l0 = __builtin_amdgcn_cvt_pk_f32_fp8((int)lq.x, false);
            const f32x2 l1 = __builtin_amdgcn_cvt_pk_f32_fp8((int)lq.x, true);
            const f32x2 l2 = __builtin_amdgcn_cvt_pk_f32_fp8((int)lq.y, false);
            const f32x2 l3 = __builtin_amdgcn_cvt_pk_f32_fp8((int)lq.y, true);
            const f32x2 r0 = __builtin_amdgcn_cvt_pk_f32_fp8((int)rq.x, false);
            const f32x2 r1 = __builtin_amdgcn_cvt_pk_f32_fp8((int)rq.x, true);
            const f32x2 r2 = __builtin_amdgcn_cvt_pk_f32_fp8((int)rq.y, false);
            const f32x2 r3 = __builtin_amdgcn_cvt_pk_f32_fp8((int)rq.y, true);
            const f32x2 u0 = __builtin_amdgcn_cvt_pk_f32_fp8((int)uq.x, false);
            const f32x2 u1 = __builtin_amdgcn_cvt_pk_f32_fp8((int)uq.x, true);
            const f32x2 u2 = __builtin_amdgcn_cvt_pk_f32_fp8((int)uq.y, false);
            const f32x2 u3 = __builtin_amdgcn_cvt_pk_f32_fp8((int)uq.y, true);
            float d;
            d = l0.x - r0.x; slr = fmaf(d, d, slr);
            d = l0.y - r0.y; slr = fmaf(d, d, slr);
            d = l1.x - r1.x; slr = fmaf(d, d, slr);
            d = l1.y - r1.y; slr = fmaf(d, d, slr);
            d = l2.x - r2.x; slr = fmaf(d, d, slr);
            d = l2.y - r2.y; slr = fmaf(d, d, slr);
            d = l3.x - r3.x; slr = fmaf(d, d, slr);
            d = l3.y - r3.y; slr = fmaf(d, d, slr);
            d = l0.x - u0.x; slu = fmaf(d, d, slu);
            d = l0.y - u0.y; slu = fmaf(d, d, slu);
            d = l1.x - u1.x; slu = fmaf(d, d, slu);
            d = l1.y - u1.y; slu = fmaf(d, d, slu);
            d = l2.x - u2.x; slu = fmaf(d, d, slu);
            d = l2.y - u2.y; slu = fmaf(d, d, slu);
            d = l3.x - u3.x; slu = fmaf(d, d, slu);
            d = l3.y - u3.y; slu = fmaf(d, d, slu);
        }
        #pragma unroll
        for (int off = 1; off < 16; off <<= 1) {
            slr += __shfl_xor(slr, off);
            slu += __shfl_xor(slu, off);
        }
        if (valid && sub == 0) {
            partial += w[e] * (rho[i] + nu[j] + tau[k] - sqrtf(slr) - sqrtf(slu));
        }
    }
    partial += __shfl_xor(partial, 16);
    partial += __shfl_xor(partial, 32);
    __shared__ float ps[4];
    if (lane == 0) ps[wv] = partial;
    __syncthreads();
    if (threadIdx.x == 0) atomicAdd(out, ps[0] + ps[1] + ps[2] + ps[3]);
}

// ---- fallback edge kernel on bf16 tables (if ws too small for fp8) ---------
__global__ __launch_bounds__(256)
void edge_kernel(const unsigned* __restrict__ Lb, const unsigned* __restrict__ Rb,
                 const unsigned* __restrict__ Ub,
                 const float* __restrict__ rho, const float* __restrict__ nu,
                 const float* __restrict__ tau, const float* __restrict__ w,
                 const int* __restrict__ si, const int* __restrict__ sj,
                 const int* __restrict__ sk, int E,
                 float* __restrict__ out) {
    const int lane = threadIdx.x & 63;
    const int wv = threadIdx.x >> 6;
    const int gwave = blockIdx.x * 4 + wv;
    const int nwaves = gridDim.x * 4;
    float partial = 0.0f;
    for (int e = gwave; e < E; e += nwaves) {
        const int i = si[e], j = sj[e], k = sk[e];
        const unsigned lv = Lb[(size_t)i * 64 + lane];
        const unsigned rv = Rb[(size_t)j * 64 + lane];
        const unsigned uv = Ub[(size_t)k * 64 + lane];
        const float l0 = __uint_as_float(lv << 16);
        const float l1 = __uint_as_float(lv & 0xffff0000u);
        const float r0 = __uint_as_float(rv << 16);
        const float r1 = __uint_as_float(rv & 0xffff0000u);
        const float u0 = __uint_as_float(uv << 16);
        const float u1 = __uint_as_float(uv & 0xffff0000u);
        const float a0 = l0 - r0, a1 = l1 - r1;
        const float b0 = l0 - u0, b1 = l1 - u1;
        float slr = a0 * a0 + a1 * a1;
        float slu = b0 * b0 + b1 * b1;
        #pragma unroll
        for (int off = 32; off > 0; off >>= 1) {
            slr += __shfl_down(slr, off);
            slu += __shfl_down(slu, off);
        }
        if (lane == 0)
            partial += w[e] * (rho[i] + nu[j] + tau[k] - sqrtf(slr) - sqrtf(slu));
    }
    __shared__ float ps[4];
    if (lane == 0) ps[wv] = partial;
    __syncthreads();
    if (threadIdx.x == 0) atomicAdd(out, ps[0] + ps[1] + ps[2] + ps[3]);
}

// ---- z_pdist1 = sum_i colRL[i] * exp(rho_i) * colUL[i] ---------------------
__global__ __launch_bounds__(256)
void combine_kernel(const float* __restrict__ colRL,
                    const float* __restrict__ colUL,
                    const float* __restrict__ rho, int nI,
                    float* __restrict__ out) {
    const int t = blockIdx.x * blockDim.x + threadIdx.x;
    float v = 0.0f;
    if (t < nI) v = colRL[t] * __expf(rho[t]) * colUL[t];
    #pragma unroll
    for (int off = 32; off > 0; off >>= 1) v += __shfl_down(v, off);
    __shared__ float ps[4];
    const int lane = threadIdx.x & 63, wv = threadIdx.x >> 6;
    if (lane == 0) ps[wv] = v;
    __syncthreads();
    if (threadIdx.x == 0) atomicAdd(out, -(ps[0] + ps[1] + ps[2] + ps[3]));
}

extern "C" void kernel_launch(void* const* d_in, const int* in_sizes, int n_in,
                              void* d_out, int out_size, void* d_ws, size_t ws_size,
                              hipStream_t stream) {
    (void)n_in; (void)out_size;
    const float* L   = (const float*)d_in[0];
    const float* R   = (const float*)d_in[1];
    const float* U   = (const float*)d_in[2];
    const float* rho = (const float*)d_in[3];
    const float* nu  = (const float*)d_in[4];
    const float* tau = (const float*)d_in[5];
    const float* w   = (const float*)d_in[6];
    const int* si = (const int*)d_in[7];
    const int* sj = (const int*)d_in[8];
    const int* sk = (const int*)d_in[9];
    const int I = in_sizes[3];
    const int J = in_sizes[4];
    const int K = in_sizes[5];
    const int E = in_sizes[6];

    float* ws    = (float*)d_ws;
    float* colRL = ws;               // I
    float* colUL = ws + I;           // I
    float* normL = ws + 2 * I;       // I
    float* normR = ws + 3 * I;       // J
    float* normU = ws + 3 * I + J;   // K
    unsigned short* Lb = (unsigned short*)(ws + 3 * (size_t)I + J + K);
    unsigned short* Rb = Lb + (size_t)I * D;
    unsigned short* Ub = Rb + (size_t)J * D;
    unsigned short* Lf8 = Ub + (size_t)K * D;       // fp8 tables, 64 ushort/row
    unsigned short* Rf8 = Lf8 + (size_t)I * 64;
    unsigned short* Uf8 = Rf8 + (size_t)J * 64;

    const size_t need = (size_t)(3 * I + J + K) * 4 +
                        (size_t)(I + J + K) * D * 2 +
                        (size_t)(I + J + K) * 128;
    const bool use_fp8 = (ws_size >= need);

    hipMemsetAsync(d_out, 0, sizeof(float), stream);
    hipMemsetAsync(colRL, 0, (size_t)2 * I * sizeof(float), stream);

    prep_kernel<<<dim3(I / 4), 256, 0, stream>>>(L, I, 0.0f, (unsigned*)Lb,
                                                 use_fp8 ? Lf8 : (unsigned short*)0, normL);
    prep_kernel<<<dim3(J / 4), 256, 0, stream>>>(R, J, EPS, (unsigned*)Rb,
                                                 use_fp8 ? Rf8 : (unsigned short*)0, normR);
    prep_kernel<<<dim3(K / 4), 256, 0, stream>>>(U, K, EPS, (unsigned*)Ub,
                                                 use_fp8 ? Uf8 : (unsigned short*)0, normU);

    dist_mfma_kernel<<<dim3(I / 128, J / 128), 256, 0, stream>>>(
        Rb, Lb, normR, normL, nu, colRL);
    dist_mfma_kernel<<<dim3(I / 128, K / 128), 256, 0, stream>>>(
        Ub, Lb, normU, normL, tau, colUL);

    if (use_fp8) {
        edge_fp8_kernel<<<dim3(2048), 256, 0, stream>>>(
            (const uint2*)Lf8, (const uint2*)Rf8, (const uint2*)Uf8,
            rho, nu, tau, w, si, sj, sk, E, (float*)d_out);
    } else {
        edge_kernel<<<dim3(4096), 256, 0, stream>>>(
            (const unsigned*)Lb, (const unsigned*)Rb, (const unsigned*)Ub,
            rho, nu, tau, w, si, sj, sk, E, (float*)d_out);
    }

    combine_kernel<<<dim3((I + 255) / 256), 256, 0, stream>>>(
        colRL, colUL, rho, I, (float*)d_out);
}